// Round 1
// baseline (564.626 us; speedup 1.0000x reference)
//
#include <hip/hip_runtime.h>

// Problem constants
#define N_NODES 49152
#define FDIM    128
#define DDIM    9
#define NB      16                       // nodes per block
#define NBLK    (N_NODES / NB)           // 3072
#define OUT2_OFF ((size_t)N_NODES * FDIM * DDIM)

// ws layout (ushort elements): Wq[3][128][128], Wk, Wv, ls_w[256][128], lvs_w[128][128]
#define WQ_OFF   0
#define WK_OFF   49152
#define WV_OFF   98304
#define LS_OFF   147456
#define LVS_OFF  180224
#define WS_ELEMS 196608

typedef __bf16 bf16x8 __attribute__((ext_vector_type(8)));
typedef float  floatx4 __attribute__((ext_vector_type(4)));

__device__ __forceinline__ unsigned short f2bf(float f) {
    unsigned u = __float_as_uint(f);
    u += 0x7FFFu + ((u >> 16) & 1u);      // RNE; inputs are finite Gaussians, no NaN handling needed
    return (unsigned short)(u >> 16);
}

__device__ __forceinline__ floatx4 mfma16(bf16x8 a, bf16x8 b, floatx4 c) {
    return __builtin_amdgcn_mfma_f32_16x16x32_bf16(a, b, c, 0, 0, 0);
}

// ---------------- prep: cast all weights to bf16 into ws ----------------
__global__ void prep_kernel(const float* __restrict__ Wq, const float* __restrict__ Wk,
                            const float* __restrict__ Wv, const float* __restrict__ lsw,
                            const float* __restrict__ lvw, unsigned short* __restrict__ ws) {
    int i = blockIdx.x * 256 + threadIdx.x;
    if (i >= WS_ELEMS) return;
    float v;
    if      (i < WK_OFF)  v = Wq[i - WQ_OFF];
    else if (i < WV_OFF)  v = Wk[i - WK_OFF];
    else if (i < LS_OFF)  v = Wv[i - WV_OFF];
    else if (i < LVS_OFF) v = lsw[i - LS_OFF];
    else                  v = lvw[i - LVS_OFF];
    ws[i] = f2bf(v);
}

// ---------------- fused main kernel ----------------
struct SMem {
    union {
        unsigned short ttr[NB * DDIM * 136];  // T transposed [n][dd][u], bf16, row pad 136 (39168 B)
        float tu8[8 * 1160];                  // tu staging for 8 nodes, pad 1160 (37120 B)
    } u;
    unsigned short sS[NB * 136];              // S bf16 [n][u]
    unsigned short sbuf[NB * 136];            // s bf16 [n][u]
    float p[NB * 273];                        // softmax probs fp32 [n][i], stride 273
    float w2l[3 * FDIM];                      // w2 fp32
    float redA[4 * 16];
    float redB[4 * 16];
};

__global__ void __launch_bounds__(256, 2)
tpattn_main(const float* __restrict__ T, const float* __restrict__ S,
            const float* __restrict__ w2, const float* __restrict__ ls_b,
            const float* __restrict__ lvs_b, const unsigned short* __restrict__ wbf,
            float* __restrict__ out) {
    __shared__ SMem sm;
    const int tid  = threadIdx.x;
    const int w    = tid >> 6;       // wave 0..3
    const int lane = tid & 63;
    const int quad = lane >> 4;
    const int m16  = lane & 15;      // node col for B/D; row for A loads
    const int n0   = blockIdx.x * NB;

    const unsigned short* Wq  = wbf + WQ_OFF;
    const unsigned short* Wk  = wbf + WK_OFF;
    const unsigned short* Wv  = wbf + WV_OFF;
    const unsigned short* Lsw = wbf + LS_OFF;
    const unsigned short* Lvw = wbf + LVS_OFF;

    constexpr int   DL[3]  = {1, 3, 5};
    constexpr int   OL[3]  = {0, 1, 4};
    constexpr float C1A[3] = {0.57735026919f, 0.33333333333f, 0.25819888975f};
    const float INV_F  = 0.0078125f;          // 1/128 (q*k scaling)
    const float INV_SF = 0.08838834764831845f; // 1/sqrt(128)

    // ---- phase 0: stage T (bf16, transposed), S (bf16), w2 ----
    {
        const float4* Tg = (const float4*)(T + (size_t)n0 * 1152);
        #pragma unroll
        for (int it = 0; it < 18; ++it) {
            int lin = (it * 256 + tid) * 4;
            float4 val = Tg[it * 256 + tid];
            float vv[4] = {val.x, val.y, val.z, val.w};
            #pragma unroll
            for (int e = 0; e < 4; ++e) {
                int le = lin + e;
                int t9 = le / 9;              // n*128 + u
                int dd = le - t9 * 9;
                int n  = t9 >> 7;
                int uu = t9 & 127;
                sm.u.ttr[(n * 9 + dd) * 136 + uu] = f2bf(vv[e]);
            }
        }
        const float4* Sg = (const float4*)(S + (size_t)n0 * 128);
        #pragma unroll
        for (int it = 0; it < 2; ++it) {
            int lin = (it * 256 + tid) * 4;
            float4 val = Sg[it * 256 + tid];
            int n = lin >> 7, uu = lin & 127;
            sm.sS[n * 136 + uu + 0] = f2bf(val.x);
            sm.sS[n * 136 + uu + 1] = f2bf(val.y);
            sm.sS[n * 136 + uu + 2] = f2bf(val.z);
            sm.sS[n * 136 + uu + 3] = f2bf(val.w);
        }
        for (int i = tid; i < 3 * FDIM; i += 256) sm.w2l[i] = w2[i];
    }
    __syncthreads();

    // ---- phase 2: q,k projections + in-lane s = sum_d C1 q k ----
    float sf[2][4] = {{0.f,0.f,0.f,0.f},{0.f,0.f,0.f,0.f}};
    #pragma unroll
    for (int l = 0; l < 3; ++l) {
        bf16x8 aq[2][4], ak[2][4];
        #pragma unroll
        for (int vt = 0; vt < 2; ++vt)
            #pragma unroll
            for (int kc = 0; kc < 4; ++kc) {
                int v  = w * 32 + vt * 16 + m16;
                int u0 = kc * 32 + quad * 8;
                aq[vt][kc] = *(const bf16x8*)(Wq + (l * 128 + v) * 128 + u0);
                ak[vt][kc] = *(const bf16x8*)(Wk + (l * 128 + v) * 128 + u0);
            }
        #pragma unroll
        for (int j = 0; j < DL[l]; ++j) {
            int jj = OL[l] + j;
            bf16x8 b[4];
            #pragma unroll
            for (int kc = 0; kc < 4; ++kc)
                b[kc] = *(const bf16x8*)(&sm.u.ttr[(m16 * 9 + jj) * 136 + kc * 32 + quad * 8]);
            floatx4 q0 = {0.f,0.f,0.f,0.f}, q1 = {0.f,0.f,0.f,0.f};
            floatx4 k0 = {0.f,0.f,0.f,0.f}, k1 = {0.f,0.f,0.f,0.f};
            #pragma unroll
            for (int kc = 0; kc < 4; ++kc) {
                q0 = mfma16(aq[0][kc], b[kc], q0);
                q1 = mfma16(aq[1][kc], b[kc], q1);
                k0 = mfma16(ak[0][kc], b[kc], k0);
                k1 = mfma16(ak[1][kc], b[kc], k1);
            }
            #pragma unroll
            for (int r = 0; r < 4; ++r) {
                sf[0][r] += C1A[l] * q0[r] * k0[r];
                sf[1][r] += C1A[l] * q1[r] * k1[r];
            }
        }
    }
    #pragma unroll
    for (int vt = 0; vt < 2; ++vt)
        #pragma unroll
        for (int r = 0; r < 4; ++r) {
            int uu = w * 32 + vt * 16 + quad * 4 + r;
            sm.sbuf[m16 * 136 + uu] = f2bf(sf[vt][r] * INV_F);
        }
    __syncthreads();

    // ---- phase 3: logits = ls_w @ s + ls_b (wave w owns rows 64w..64w+63) ----
    float lg[4][4];
    {
        bf16x8 bs[4];
        #pragma unroll
        for (int kc = 0; kc < 4; ++kc)
            bs[kc] = *(const bf16x8*)(&sm.sbuf[m16 * 136 + kc * 32 + quad * 8]);
        #pragma unroll
        for (int rt = 0; rt < 4; ++rt) {
            floatx4 acc = {0.f,0.f,0.f,0.f};
            int ia = (4 * w + rt) * 16 + m16;
            #pragma unroll
            for (int kc = 0; kc < 4; ++kc) {
                bf16x8 a = *(const bf16x8*)(Lsw + ia * 128 + kc * 32 + quad * 8);
                acc = mfma16(a, bs[kc], acc);
            }
            int i0 = (4 * w + rt) * 16 + quad * 4;
            float4 bias = *(const float4*)(ls_b + i0);
            lg[rt][0] = acc[0] + bias.x;
            lg[rt][1] = acc[1] + bias.y;
            lg[rt][2] = acc[2] + bias.z;
            lg[rt][3] = acc[3] + bias.w;
        }
    }

    // ---- phase 4: softmax over 256 per node (col = m16) ----
    {
        float mx = lg[0][0];
        #pragma unroll
        for (int rt = 0; rt < 4; ++rt)
            #pragma unroll
            for (int r = 0; r < 4; ++r) mx = fmaxf(mx, lg[rt][r]);
        mx = fmaxf(mx, __shfl_xor(mx, 16, 64));
        mx = fmaxf(mx, __shfl_xor(mx, 32, 64));
        if (lane < 16) sm.redA[w * 16 + lane] = mx;
        __syncthreads();
        float m4 = fmaxf(fmaxf(sm.redA[m16], sm.redA[16 + m16]),
                         fmaxf(sm.redA[32 + m16], sm.redA[48 + m16]));
        float lsum = 0.f;
        #pragma unroll
        for (int rt = 0; rt < 4; ++rt)
            #pragma unroll
            for (int r = 0; r < 4; ++r) {
                float e = __expf(lg[rt][r] - m4);
                lg[rt][r] = e;
                lsum += e;
            }
        lsum += __shfl_xor(lsum, 16, 64);
        lsum += __shfl_xor(lsum, 32, 64);
        if (lane < 16) sm.redB[w * 16 + lane] = lsum;
        __syncthreads();
        float tot = sm.redB[m16] + sm.redB[16 + m16] + sm.redB[32 + m16] + sm.redB[48 + m16];
        float rinv = 1.0f / tot;
        #pragma unroll
        for (int rt = 0; rt < 4; ++rt)
            #pragma unroll
            for (int r = 0; r < 4; ++r)
                sm.p[m16 * 273 + (4 * w + rt) * 16 + quad * 4 + r] = lg[rt][r] * rinv;
    }
    __syncthreads();

    // ---- phase 5: v projection (accumulate all 9 dims in regs), tu staging + coalesced store ----
    float sdv[2][4];
    float w2v[3][2][4];
    #pragma unroll
    for (int vt = 0; vt < 2; ++vt)
        #pragma unroll
        for (int r = 0; r < 4; ++r) {
            int uu = w * 32 + vt * 16 + quad * 4 + r;
            sdv[vt][r] = sm.p[m16 * 273 + 128 + uu] * INV_SF;  // sd * 1/sqrt(F) folded
            #pragma unroll
            for (int l = 0; l < 3; ++l) w2v[l][vt][r] = sm.w2l[l * 128 + uu];
        }

    floatx4 vacc[9][2];
    #pragma unroll
    for (int l = 0; l < 3; ++l) {
        bf16x8 av[2][4];
        #pragma unroll
        for (int vt = 0; vt < 2; ++vt)
            #pragma unroll
            for (int kc = 0; kc < 4; ++kc) {
                int v  = w * 32 + vt * 16 + m16;
                int u0 = kc * 32 + quad * 8;
                av[vt][kc] = *(const bf16x8*)(Wv + (l * 128 + v) * 128 + u0);
            }
        #pragma unroll
        for (int j = 0; j < DL[l]; ++j) {
            int jj = OL[l] + j;
            bf16x8 b[4];
            #pragma unroll
            for (int kc = 0; kc < 4; ++kc)
                b[kc] = *(const bf16x8*)(&sm.u.ttr[(m16 * 9 + jj) * 136 + kc * 32 + quad * 8]);
            floatx4 a0 = {0.f,0.f,0.f,0.f}, a1 = {0.f,0.f,0.f,0.f};
            #pragma unroll
            for (int kc = 0; kc < 4; ++kc) {
                a0 = mfma16(av[0][kc], b[kc], a0);
                a1 = mfma16(av[1][kc], b[kc], a1);
            }
            vacc[jj][0] = a0;
            vacc[jj][1] = a1;
        }
    }
    __syncthreads();   // all waves done reading ttr; safe to reuse as tu staging

    #pragma unroll
    for (int h = 0; h < 2; ++h) {
        if (((m16 >> 3) & 1) == h) {
            int n8 = m16 & 7;
            #pragma unroll
            for (int l = 0; l < 3; ++l)
                #pragma unroll
                for (int j = 0; j < DL[l]; ++j) {
                    int jj = OL[l] + j;
                    #pragma unroll
                    for (int vt = 0; vt < 2; ++vt)
                        #pragma unroll
                        for (int r = 0; r < 4; ++r) {
                            int uu = w * 32 + vt * 16 + quad * 4 + r;
                            sm.u.tu8[n8 * 1160 + uu * 9 + jj] =
                                vacc[jj][vt][r] * sdv[vt][r] * w2v[l][vt][r];
                        }
                }
        }
        __syncthreads();
        float* outt = out + (size_t)(n0 + h * 8) * 1152;
        #pragma unroll
        for (int it = 0; it < 9; ++it) {
            int lin = it * 1024 + tid * 4;
            int n8  = lin / 1152;
            int r   = lin - n8 * 1152;
            float4 v4 = *(const float4*)(&sm.u.tu8[n8 * 1160 + r]);
            *(float4*)(outt + (size_t)n8 * 1152 + r) = v4;
        }
        __syncthreads();
    }

    // ---- phase 6: out2 = su * silu(S @ lvs_w.T + lvs_b) ----
    {
        bf16x8 bS[4];
        #pragma unroll
        for (int kc = 0; kc < 4; ++kc)
            bS[kc] = *(const bf16x8*)(&sm.sS[m16 * 136 + kc * 32 + quad * 8]);
        #pragma unroll
        for (int rt = 0; rt < 2; ++rt) {
            floatx4 acc = {0.f,0.f,0.f,0.f};
            int ia = (2 * w + rt) * 16 + m16;
            #pragma unroll
            for (int kc = 0; kc < 4; ++kc) {
                bf16x8 a = *(const bf16x8*)(Lvw + ia * 128 + kc * 32 + quad * 8);
                acc = mfma16(a, bS[kc], acc);
            }
            int i0 = (2 * w + rt) * 16 + quad * 4;
            float4 bias = *(const float4*)(lvs_b + i0);
            float bb[4] = {bias.x, bias.y, bias.z, bias.w};
            float o4[4];
            #pragma unroll
            for (int r = 0; r < 4; ++r) {
                float z   = acc[r] + bb[r];
                float sig = 1.0f / (1.0f + __expf(-z));
                float su  = sm.p[m16 * 273 + i0 + r];
                o4[r] = su * z * sig;
            }
            *(float4*)(out + OUT2_OFF + (size_t)(n0 + m16) * 128 + i0) =
                make_float4(o4[0], o4[1], o4[2], o4[3]);
        }
    }
}

extern "C" void kernel_launch(void* const* d_in, const int* in_sizes, int n_in,
                              void* d_out, int out_size, void* d_ws, size_t ws_size,
                              hipStream_t stream) {
    const float* T   = (const float*)d_in[0];
    const float* S   = (const float*)d_in[1];
    const float* Wq  = (const float*)d_in[2];
    const float* Wk  = (const float*)d_in[3];
    const float* Wv  = (const float*)d_in[4];
    const float* w2  = (const float*)d_in[5];
    const float* lsw = (const float*)d_in[6];
    const float* lsb = (const float*)d_in[7];
    const float* lvw = (const float*)d_in[8];
    const float* lvb = (const float*)d_in[9];
    float* out = (float*)d_out;
    unsigned short* wbf = (unsigned short*)d_ws;

    if (ws_size < WS_ELEMS * sizeof(unsigned short)) return;  // workspace guard (needs 384 KB)

    prep_kernel<<<(WS_ELEMS + 255) / 256, 256, 0, stream>>>(Wq, Wk, Wv, lsw, lvw, wbf);
    tpattn_main<<<NBLK, 256, 0, stream>>>(T, S, w2, lsb, lvb, wbf, out);
}